// Round 1
// baseline (137.147 us; speedup 1.0000x reference)
//
#include <hip/hip_runtime.h>

typedef unsigned short u16;
typedef short s8v __attribute__((ext_vector_type(8)));
typedef float f4v __attribute__((ext_vector_type(4)));

#define DIM 2048      // d_model = K
#define NW  640       // padded weight rows: 512 dt_w + 16 B^T + 112 zeros
#define LDG 640

__device__ __forceinline__ u16 f2bf(float f) {
  unsigned u = __float_as_uint(f);
  u += 0x7fffu + ((u >> 16) & 1u);
  return (u16)(u >> 16);
}

__device__ __forceinline__ void async16(const void* g, void* l) {
  __builtin_amdgcn_global_load_lds((const __attribute__((address_space(1))) void*)g,
                                   (__attribute__((address_space(3))) void*)l, 16, 0, 0);
}

// ---------------- kernel 1: x f32 -> bf16 ----------------
__global__ void cvt_x(const float* __restrict__ x, u16* __restrict__ xb, long n4) {
  long i = (long)blockIdx.x * blockDim.x + threadIdx.x;
  long stride = (long)gridDim.x * blockDim.x;
  for (; i < n4; i += stride) {
    float4 v = ((const float4*)x)[i];
    ushort4 o;
    o.x = f2bf(v.x); o.y = f2bf(v.y); o.z = f2bf(v.z); o.w = f2bf(v.w);
    ((ushort4*)xb)[i] = o;
  }
}

// ---------------- kernel 2: build padded weight (640 x 2048) bf16 ----------------
__global__ void cvt_w(const float* __restrict__ dtw, const float* __restrict__ Bm,
                      u16* __restrict__ W) {
  long total = (long)NW * DIM;
  long i = (long)blockIdx.x * blockDim.x + threadIdx.x;
  long stride = (long)gridDim.x * blockDim.x;
  for (; i < total; i += stride) {
    int row = (int)(i >> 11);
    int k   = (int)(i & 2047);
    float v;
    if (row < 512)      v = dtw[i];                    // dt_w is (512,2048) row-major
    else if (row < 528) v = Bm[(long)k * 16 + (row - 512)];  // B^T
    else                v = 0.f;
    W[i] = f2bf(v);
  }
}

// ---------------- kernel 3: GEMM  G[8192][640] = x_bf16 (8192x2048) * W^T ----------------
__global__ __launch_bounds__(256) void gemm_bt(const u16* __restrict__ A,
                                               const u16* __restrict__ W,
                                               float* __restrict__ G) {
  __shared__ u16 As[2][128 * 32];
  __shared__ u16 Bs[2][128 * 32];
  const int t  = threadIdx.x;
  const int l  = t & 63;
  const int wv = t >> 6;
  const int wr = wv >> 1, wc = wv & 1;          // 2x2 waves, each 64x64
  const int arow0 = blockIdx.y * 128;
  const int brow0 = blockIdx.x * 128;
  const int srow = t >> 2;                      // staging: row within 64-row pass
  const int scol = (t & 3) * 8;                 // 8 bf16 = 16B per load
  const int lr = l & 15, lh = l >> 4;

  f4v acc[4][4];
#pragma unroll
  for (int i = 0; i < 4; ++i)
#pragma unroll
    for (int j = 0; j < 4; ++j) acc[i][j] = (f4v){0.f, 0.f, 0.f, 0.f};

  const u16* ga0 = A + (arow0 + srow) * DIM + scol;
  const u16* gb0 = W + (brow0 + srow) * DIM + scol;

#define STAGE(buf, kt) do {                                  \
    const u16* ga = ga0 + (kt) * 32;                         \
    const u16* gb = gb0 + (kt) * 32;                         \
    async16(ga,            &As[buf][t * 8]);                 \
    async16(ga + 64 * DIM, &As[buf][2048 + t * 8]);          \
    async16(gb,            &Bs[buf][t * 8]);                 \
    async16(gb + 64 * DIM, &Bs[buf][2048 + t * 8]);          \
  } while (0)

  STAGE(0, 0);
  __syncthreads();
  int buf = 0;
  for (int kt = 0; kt < 64; ++kt) {
    if (kt + 1 < 64) STAGE(buf ^ 1, kt + 1);
    s8v a[4], b[4];
#pragma unroll
    for (int i = 0; i < 4; ++i)
      a[i] = *(const s8v*)&As[buf][(wr * 64 + i * 16 + lr) * 32 + lh * 8];
#pragma unroll
    for (int j = 0; j < 4; ++j)
      b[j] = *(const s8v*)&Bs[buf][(wc * 64 + j * 16 + lr) * 32 + lh * 8];
#pragma unroll
    for (int i = 0; i < 4; ++i)
#pragma unroll
      for (int j = 0; j < 4; ++j)
        acc[i][j] = __builtin_amdgcn_mfma_f32_16x16x32_bf16(a[i], b[j], acc[i][j], 0, 0, 0);
    __syncthreads();
    buf ^= 1;
  }
#undef STAGE

#pragma unroll
  for (int i = 0; i < 4; ++i)
#pragma unroll
    for (int j = 0; j < 4; ++j) {
      int row = arow0 + wr * 64 + i * 16 + lh * 4;
      int col = brow0 + wc * 64 + j * 16 + lr;
      float* gp = G + row * LDG + col;
#pragma unroll
      for (int q = 0; q < 4; ++q) gp[q * LDG] = acc[i][j][q];
    }
}

// ---------------- kernel 4: delta2 + sigmoid + A_bar ----------------
__global__ __launch_bounds__(256) void delta_abar(const float* __restrict__ G,
                                                  const float* __restrict__ pw,
                                                  const float* __restrict__ dtb,
                                                  const float* __restrict__ Alog,
                                                  float* __restrict__ abar) {
  const int wv = threadIdx.x >> 6, l = threadIdx.x & 63;
  const int m = blockIdx.x * 4 + wv;            // 2048 blocks * 4 waves = 8192 rows
  const int n = l & 15, seg = l >> 4;
  const float* g = G + (long)m * LDG + seg * 128;
  float s = 0.f;
#pragma unroll 4
  for (int r = 0; r < 128; ++r) {
    int rr = seg * 128 + r;
    s += (g[r] + dtb[rr]) * pw[rr * 16 + n];
  }
  s += __shfl_down(s, 32);
  s += __shfl_down(s, 16);
  if (l < 16) {
    float sig = 1.f / (1.f + __expf(-s));
    float delta = 0.001f + 0.099f * sig;
    float Av = __expf(Alog[n]);
    abar[(long)m * 16 + n] = __expf(delta * Av);
  }
}

// ---------------- kernel 5: scan over s per (b,n) ----------------
__global__ __launch_bounds__(256) void scan_k(const float* __restrict__ abar,
                                              const float* __restrict__ G,
                                              float* __restrict__ hs) {
  const int b = blockIdx.x >> 4, n = blockIdx.x & 15;  // 64 blocks
  const int t = threadIdx.x;                           // 256 threads, 8 steps each
  __shared__ float sA[256], sX[256];
  const long base = (long)b * 2048;
  float a[8], x[8];
  float Ac = 1.f, Xc = 0.f;
#pragma unroll
  for (int i = 0; i < 8; ++i) {
    long s = (long)t * 8 + i;
    a[i] = abar[(base + s) * 16 + n];
    x[i] = G[(base + s) * LDG + 512 + n];
    Xc = a[i] * Xc + x[i];
    Ac *= a[i];
  }
  sA[t] = Ac; sX[t] = Xc;
  __syncthreads();
  for (int off = 1; off < 256; off <<= 1) {
    float pa = 1.f, px = 0.f;
    bool en = (t >= off);
    if (en) { pa = sA[t - off]; px = sX[t - off]; }
    __syncthreads();
    if (en) { sX[t] = sA[t] * px + sX[t]; sA[t] *= pa; }
    __syncthreads();
  }
  float h = (t == 0) ? 0.f : sX[t - 1];
#pragma unroll
  for (int i = 0; i < 8; ++i) {
    h = a[i] * h + x[i];
    hs[(base + (long)t * 8 + i) * 16 + n] = h;
  }
}

// ---------------- kernel 6: y = hs @ C ----------------
__global__ __launch_bounds__(512) void proj(const float* __restrict__ hs,
                                            const float* __restrict__ C,
                                            float* __restrict__ y) {
  __shared__ float sh[32 * 16];
  const int t = threadIdx.x;                 // 512 threads, 4 cols each
  const long row0 = (long)blockIdx.x * 32;   // 256 blocks
  sh[t] = hs[row0 * 16 + t];
  float4 c[16];
#pragma unroll
  for (int nn = 0; nn < 16; ++nn) c[nn] = *(const float4*)&C[nn * 2048 + t * 4];
  __syncthreads();
#pragma unroll 4
  for (int r = 0; r < 32; ++r) {
    const float* h = &sh[r * 16];
    float4 o = {0.f, 0.f, 0.f, 0.f};
#pragma unroll
    for (int nn = 0; nn < 16; ++nn) {
      float hv = h[nn];
      o.x += hv * c[nn].x; o.y += hv * c[nn].y;
      o.z += hv * c[nn].z; o.w += hv * c[nn].w;
    }
    *(float4*)&y[(row0 + r) * 2048 + t * 4] = o;
  }
}

extern "C" void kernel_launch(void* const* d_in, const int* in_sizes, int n_in,
                              void* d_out, int out_size, void* d_ws, size_t ws_size,
                              hipStream_t stream) {
  const float* x    = (const float*)d_in[0];
  const float* Alog = (const float*)d_in[1];
  const float* Bm   = (const float*)d_in[2];
  const float* Cm   = (const float*)d_in[3];
  const float* dtw  = (const float*)d_in[4];
  const float* dtb  = (const float*)d_in[5];
  const float* dtpw = (const float*)d_in[6];
  float* y = (float*)d_out;

  char* w = (char*)d_ws;
  u16*   xb = (u16*)w;   w += (size_t)8192 * 2048 * 2;   // 33.6 MB
  u16*   Wt = (u16*)w;   w += (size_t)NW * 2048 * 2;     //  2.6 MB
  float* G  = (float*)w; w += (size_t)8192 * LDG * 4;    // 21.0 MB
  float* ab = (float*)w; w += (size_t)8192 * 16 * 4;     //  0.5 MB
  float* hs = (float*)w; w += (size_t)8192 * 16 * 4;     //  0.5 MB

  cvt_x<<<2048, 256, 0, stream>>>(x, xb, (long)(8192L * 2048 / 4));
  cvt_w<<<1024, 256, 0, stream>>>(dtw, Bm, Wt);
  gemm_bt<<<dim3(5, 64), 256, 0, stream>>>(xb, Wt, G);
  delta_abar<<<2048, 256, 0, stream>>>(G, dtpw, dtb, Alog, ab);
  scan_k<<<64, 256, 0, stream>>>(ab, G, hs);
  proj<<<256, 512, 0, stream>>>(hs, Cm, y);
}

// Round 2
// 80.251 us; speedup vs baseline: 1.7090x; 1.7090x over previous
//
#include <hip/hip_runtime.h>

typedef unsigned short u16;
typedef short s8v __attribute__((ext_vector_type(8)));
typedef float f4v __attribute__((ext_vector_type(4)));

#define DMODEL 2048

__device__ __forceinline__ u16 f2bf(float f) {
  unsigned u = __float_as_uint(f);
  u += 0x7fffu + ((u >> 16) & 1u);
  return (u16)(u >> 16);
}

// ---------------- kernel 1: Wcb[32][2048] bf16 (k-contiguous rows) ----------------
// row n<16 : W2[k][n] = sum_r dt_w[r][k] * dt_pw[r][n]   (pre-associated delta proj)
// row 16+n : B[k][n]
// bias2[n] = sum_r dt_b[r] * dt_pw[r][n]
__global__ __launch_bounds__(256) void build_wc(const float* __restrict__ dtw,
                                                const float* __restrict__ dtpw,
                                                const float* __restrict__ dtb,
                                                const float* __restrict__ Bm,
                                                u16* __restrict__ Wcb,
                                                float* __restrict__ bias2) {
  const int t = threadIdx.x;
  const int k = blockIdx.x * 16 + (t >> 4);
  const int n = t & 15;
  float a0 = 0.f, a1 = 0.f, a2 = 0.f, a3 = 0.f;
#pragma unroll 4
  for (int r = 0; r < 512; r += 4) {
    a0 += dtw[(r + 0) * DMODEL + k] * dtpw[(r + 0) * 16 + n];
    a1 += dtw[(r + 1) * DMODEL + k] * dtpw[(r + 1) * 16 + n];
    a2 += dtw[(r + 2) * DMODEL + k] * dtpw[(r + 2) * 16 + n];
    a3 += dtw[(r + 3) * DMODEL + k] * dtpw[(r + 3) * 16 + n];
  }
  Wcb[n * DMODEL + k] = f2bf((a0 + a1) + (a2 + a3));
  Wcb[(16 + n) * DMODEL + k] = f2bf(Bm[k * 16 + n]);
  if (blockIdx.x == 0 && t < 16) {
    float s = 0.f;
    for (int r = 0; r < 512; ++r) s += dtb[r] * dtpw[r * 16 + t];
    bias2[t] = s;
  }
}

// ---------------- kernel 2: fused  x -> (abar_t, xb_t) ----------------
// block = 512 thr (8 waves), 16 rows of x; wave w owns K-chunk [w*256, w*256+256)
// dual 16x16x32 MFMA (delta cols | B cols), LDS reduce, activation inline.
// outputs transposed: abar_t/xb_t [(b*16+n)][s]  (64 x 2048 f32)
__global__ __launch_bounds__(512) void fused_main(const float* __restrict__ x,
                                                  const u16* __restrict__ Wcb,
                                                  const float* __restrict__ bias2,
                                                  const float* __restrict__ Alog,
                                                  float* __restrict__ abar_t,
                                                  float* __restrict__ xb_t) {
  __shared__ float red[8][64][8];
  const int t = threadIdx.x, w = t >> 6, l = t & 63;
  const int lr = l & 15, lh = l >> 4;
  const int row0 = blockIdx.x * 16;
  const int k0 = w * 256;

  f4v acc0 = {0.f, 0.f, 0.f, 0.f}, acc1 = {0.f, 0.f, 0.f, 0.f};
  const float* xp  = x + (long)(row0 + lr) * DMODEL + k0 + lh * 8;
  const u16*   wp0 = Wcb + lr * DMODEL + k0 + lh * 8;          // delta weights
  const u16*   wp1 = Wcb + (16 + lr) * DMODEL + k0 + lh * 8;   // B weights

#pragma unroll
  for (int ks = 0; ks < 8; ++ks) {
    float4 u0 = *(const float4*)(xp + ks * 32);
    float4 u1 = *(const float4*)(xp + ks * 32 + 4);
    s8v a;
    a[0] = (short)f2bf(u0.x); a[1] = (short)f2bf(u0.y);
    a[2] = (short)f2bf(u0.z); a[3] = (short)f2bf(u0.w);
    a[4] = (short)f2bf(u1.x); a[5] = (short)f2bf(u1.y);
    a[6] = (short)f2bf(u1.z); a[7] = (short)f2bf(u1.w);
    s8v b0 = *(const s8v*)(wp0 + ks * 32);
    s8v b1 = *(const s8v*)(wp1 + ks * 32);
    acc0 = __builtin_amdgcn_mfma_f32_16x16x32_bf16(a, b0, acc0, 0, 0, 0);
    acc1 = __builtin_amdgcn_mfma_f32_16x16x32_bf16(a, b1, acc1, 0, 0, 0);
  }
  *(f4v*)&red[w][l][0] = acc0;
  *(f4v*)&red[w][l][4] = acc1;
  __syncthreads();

  if (w == 0) {
    f4v s0 = {0.f, 0.f, 0.f, 0.f}, s1 = {0.f, 0.f, 0.f, 0.f};
#pragma unroll
    for (int ww = 0; ww < 8; ++ww) {
      s0 += *(const f4v*)&red[ww][l][0];
      s1 += *(const f4v*)&red[ww][l][4];
    }
    const int col = lr;
    const int b = row0 >> 11;          // batch (rows 16-aligned, never straddle)
    const int srow = row0 & 2047;
    const float bia = bias2[col];
    const float Aexp = __expf(Alog[col]);
    float* ap = abar_t + ((long)b * 16 + col) * 2048 + srow;
    float* xp2 = xb_t + ((long)b * 16 + col) * 2048 + srow;
#pragma unroll
    for (int q = 0; q < 4; ++q) {
      const int row = lh * 4 + q;
      float d2 = s0[q] + bia;
      float sig = 1.f / (1.f + __expf(-d2));
      float delta = 0.001f + 0.099f * sig;
      ap[row] = __expf(delta * Aexp);
      xp2[row] = s1[q];
    }
  }
}

// ---------------- kernel 3: scan over s per (b,n), coalesced ----------------
__global__ __launch_bounds__(256) void scan_k(const float* __restrict__ abar_t,
                                              const float* __restrict__ xb_t,
                                              float* __restrict__ hs_t) {
  const int t = threadIdx.x;
  const long base = (long)blockIdx.x * 2048;   // blockIdx = b*16+n
  __shared__ float sA[256], sX[256];
  float a[8], xv[8];
  *(float4*)&a[0]  = *(const float4*)&abar_t[base + t * 8];
  *(float4*)&a[4]  = *(const float4*)&abar_t[base + t * 8 + 4];
  *(float4*)&xv[0] = *(const float4*)&xb_t[base + t * 8];
  *(float4*)&xv[4] = *(const float4*)&xb_t[base + t * 8 + 4];
  float Ac = 1.f, Xc = 0.f;
#pragma unroll
  for (int i = 0; i < 8; ++i) { Xc = a[i] * Xc + xv[i]; Ac *= a[i]; }
  sA[t] = Ac; sX[t] = Xc;
  __syncthreads();
  for (int off = 1; off < 256; off <<= 1) {
    float pa = 1.f, px = 0.f;
    bool en = (t >= off);
    if (en) { pa = sA[t - off]; px = sX[t - off]; }
    __syncthreads();
    if (en) { sX[t] = sA[t] * px + sX[t]; sA[t] *= pa; }
    __syncthreads();
  }
  float h = (t == 0) ? 0.f : sX[t - 1];
  float o[8];
#pragma unroll
  for (int i = 0; i < 8; ++i) { h = a[i] * h + xv[i]; o[i] = h; }
  *(float4*)&hs_t[base + t * 8]     = *(const float4*)&o[0];
  *(float4*)&hs_t[base + t * 8 + 4] = *(const float4*)&o[4];
}

// ---------------- kernel 4: y = hs @ C  (reads transposed hs) ----------------
__global__ __launch_bounds__(512) void proj(const float* __restrict__ hs_t,
                                            const float* __restrict__ C,
                                            float* __restrict__ y) {
  __shared__ float sh[32 * 16];
  const int t = threadIdx.x;
  const int bB = blockIdx.x >> 6;            // batch
  const int s0 = (blockIdx.x & 63) * 32;     // s-offset
  const long row0 = (long)blockIdx.x * 32;   // global row (b,s flattened)
  {
    const int r = t >> 4, nn = t & 15;
    sh[r * 16 + nn] = hs_t[((long)bB * 16 + nn) * 2048 + s0 + r];
  }
  float4 c[16];
#pragma unroll
  for (int nn = 0; nn < 16; ++nn) c[nn] = *(const float4*)&C[nn * DMODEL + t * 4];
  __syncthreads();
#pragma unroll 4
  for (int r = 0; r < 32; ++r) {
    const float* h = &sh[r * 16];
    float4 o = {0.f, 0.f, 0.f, 0.f};
#pragma unroll
    for (int nn = 0; nn < 16; ++nn) {
      float hv = h[nn];
      o.x += hv * c[nn].x; o.y += hv * c[nn].y;
      o.z += hv * c[nn].z; o.w += hv * c[nn].w;
    }
    *(float4*)&y[(row0 + r) * DMODEL + t * 4] = o;
  }
}

extern "C" void kernel_launch(void* const* d_in, const int* in_sizes, int n_in,
                              void* d_out, int out_size, void* d_ws, size_t ws_size,
                              hipStream_t stream) {
  const float* x    = (const float*)d_in[0];
  const float* Alog = (const float*)d_in[1];
  const float* Bm   = (const float*)d_in[2];
  const float* Cm   = (const float*)d_in[3];
  const float* dtw  = (const float*)d_in[4];
  const float* dtb  = (const float*)d_in[5];
  const float* dtpw = (const float*)d_in[6];
  float* y = (float*)d_out;

  char* w = (char*)d_ws;
  u16*   Wcb   = (u16*)w;   w += (size_t)32 * DMODEL * 2;      // 128 KB
  float* bias2 = (float*)w; w += 256;                          // 16 f32 (padded)
  float* ab_t  = (float*)w; w += (size_t)64 * 2048 * 4;        // 512 KB
  float* xb_t  = (float*)w; w += (size_t)64 * 2048 * 4;        // 512 KB
  float* hs_t  = (float*)w; w += (size_t)64 * 2048 * 4;        // 512 KB

  build_wc<<<128, 256, 0, stream>>>(dtw, dtpw, dtb, Bm, Wcb, bias2);
  fused_main<<<512, 512, 0, stream>>>(x, Wcb, bias2, Alog, ab_t, xb_t);
  scan_k<<<64, 256, 0, stream>>>(ab_t, xb_t, hs_t);
  proj<<<256, 512, 0, stream>>>(hs_t, Cm, y);
}

// Round 3
// 67.596 us; speedup vs baseline: 2.0289x; 1.1872x over previous
//
#include <hip/hip_runtime.h>
#include <hip/hip_bf16.h>

typedef unsigned short u16;
typedef unsigned int u32;
typedef short s8v __attribute__((ext_vector_type(8)));
typedef float f4v __attribute__((ext_vector_type(4)));

#define DMODEL 2048

__device__ __forceinline__ u16 f2bf(float f) {
  unsigned u = __float_as_uint(f);
  u += 0x7fffu + ((u >> 16) & 1u);
  return (u16)(u >> 16);
}

__device__ __forceinline__ u32 pkbf(float lo, float hi) {
  __hip_bfloat162 h = __float22bfloat162_rn(make_float2(lo, hi));
  return *reinterpret_cast<const u32*>(&h);
}

// ---------------- kernel 1: Wcb[32][2048] bf16 (k-contiguous rows) ----------------
// row n<16 : W2[k][n] = sum_r dt_w[r][k] * dt_pw[r][n]
// row 16+n : B[k][n];  bias2[n] = sum_r dt_b[r] * dt_pw[r][n]
// 128 blocks x 256 thr; block owns 16 k-columns; LDS-staged coalesced dtw tiles.
__global__ __launch_bounds__(256) void build_wc(const float* __restrict__ dtw,
                                                const float* __restrict__ dtpw,
                                                const float* __restrict__ dtb,
                                                const float* __restrict__ Bm,
                                                u16* __restrict__ Wcb,
                                                float* __restrict__ bias2) {
  __shared__ float spw[512 * 16];   // dt_pw, 32 KB
  __shared__ float sdw[64][16];     // dtw tile, 4 KB
  const int t = threadIdx.x;
  const int k0 = blockIdx.x * 16;
  for (int i = t; i < 2048; i += 256)
    *(float4*)&spw[i * 4] = *(const float4*)&dtpw[i * 4];
  const int kk = t >> 4, n = t & 15;
  const int srr = t >> 2, sc4 = (t & 3) * 4;
  float acc = 0.f;
  for (int rc = 0; rc < 8; ++rc) {
    __syncthreads();
    *(float4*)&sdw[srr][sc4] = *(const float4*)&dtw[(rc * 64 + srr) * DMODEL + k0 + sc4];
    __syncthreads();
#pragma unroll 8
    for (int rr = 0; rr < 64; ++rr)
      acc += sdw[rr][kk] * spw[(rc * 64 + rr) * 16 + n];
  }
  Wcb[n * DMODEL + k0 + kk] = f2bf(acc);
  Wcb[(16 + n) * DMODEL + k0 + kk] = f2bf(Bm[(k0 + kk) * 16 + n]);
  if (blockIdx.x == 0 && t < 16) {
    float s0 = 0.f, s1 = 0.f;
    for (int r = 0; r < 512; r += 2) {
      s0 += dtb[r] * spw[r * 16 + t];
      s1 += dtb[r + 1] * spw[(r + 1) * 16 + t];
    }
    bias2[t] = s0 + s1;
  }
}

// ---------------- kernel 2: fused  x -> (abar_t, xb_t) ----------------
// 512 blocks x 8 waves; block = 16 x-rows; wave w owns K-chunk [w*256, w*256+256).
// Tail: wave w reduces accumulator component w (all 8 waves busy).
__global__ __launch_bounds__(512) void fused_main(const float* __restrict__ x,
                                                  const u16* __restrict__ Wcb,
                                                  const float* __restrict__ bias2,
                                                  const float* __restrict__ Alog,
                                                  float* __restrict__ abar_t,
                                                  float* __restrict__ xb_t) {
  __shared__ float red[8][8][64];   // [component][wave][lane], 16 KB
  const int t = threadIdx.x, w = t >> 6, l = t & 63;
  const int lr = l & 15, lh = l >> 4;
  const int row0 = blockIdx.x * 16;
  const int k0 = w * 256;

  f4v acc0 = {0.f, 0.f, 0.f, 0.f}, acc1 = {0.f, 0.f, 0.f, 0.f};
  const float* xp  = x + (long)(row0 + lr) * DMODEL + k0 + lh * 8;
  const u16*   wp0 = Wcb + lr * DMODEL + k0 + lh * 8;
  const u16*   wp1 = Wcb + (16 + lr) * DMODEL + k0 + lh * 8;

#pragma unroll
  for (int ks = 0; ks < 8; ++ks) {
    float4 u0 = *(const float4*)(xp + ks * 32);
    float4 u1 = *(const float4*)(xp + ks * 32 + 4);
    union { u32 d[4]; s8v v; } pa;
    pa.d[0] = pkbf(u0.x, u0.y); pa.d[1] = pkbf(u0.z, u0.w);
    pa.d[2] = pkbf(u1.x, u1.y); pa.d[3] = pkbf(u1.z, u1.w);
    s8v b0 = *(const s8v*)(wp0 + ks * 32);
    s8v b1 = *(const s8v*)(wp1 + ks * 32);
    acc0 = __builtin_amdgcn_mfma_f32_16x16x32_bf16(pa.v, b0, acc0, 0, 0, 0);
    acc1 = __builtin_amdgcn_mfma_f32_16x16x32_bf16(pa.v, b1, acc1, 0, 0, 0);
  }
#pragma unroll
  for (int q = 0; q < 4; ++q) { red[q][w][l] = acc0[q]; red[4 + q][w][l] = acc1[q]; }
  __syncthreads();

  float s = 0.f;
#pragma unroll
  for (int ww = 0; ww < 8; ++ww) s += red[w][ww][l];

  const int n = lr;
  const int row = lh * 4 + (w & 3);
  const int b = row0 >> 11, srow = row0 & 2047;
  const long idx = ((long)b * 16 + n) * 2048 + srow + row;
  if (w < 4) {
    float d2 = s + bias2[n];
    float sig = 1.f / (1.f + __expf(-d2));
    float delta = 0.001f + 0.099f * sig;
    abar_t[idx] = __expf(delta * __expf(Alog[n]));
  } else {
    xb_t[idx] = s;
  }
}

// ---------------- kernel 3: scan over s per (b,n) — shuffle-based ----------------
__global__ __launch_bounds__(256) void scan_k(const float* __restrict__ abar_t,
                                              const float* __restrict__ xb_t,
                                              float* __restrict__ hs_t) {
  const int t = threadIdx.x, w = t >> 6, lane = t & 63;
  const long base = (long)blockIdx.x * 2048;
  __shared__ float wA[4], wX[4];
  float a[8], xv[8];
  *(float4*)&a[0]  = *(const float4*)&abar_t[base + t * 8];
  *(float4*)&a[4]  = *(const float4*)&abar_t[base + t * 8 + 4];
  *(float4*)&xv[0] = *(const float4*)&xb_t[base + t * 8];
  *(float4*)&xv[4] = *(const float4*)&xb_t[base + t * 8 + 4];
  float Ac = 1.f, Xc = 0.f;
#pragma unroll
  for (int i = 0; i < 8; ++i) { Xc = a[i] * Xc + xv[i]; Ac *= a[i]; }
  // inclusive wave scan of (A,X) composition
#pragma unroll
  for (int d = 1; d < 64; d <<= 1) {
    float pa = __shfl_up(Ac, d);
    float px = __shfl_up(Xc, d);
    if (lane >= d) { Xc = Ac * px + Xc; Ac = Ac * pa; }
  }
  if (lane == 63) { wA[w] = Ac; wX[w] = Xc; }
  __syncthreads();
  float Xp = 0.f;
  for (int ww = 0; ww < w; ++ww) Xp = wA[ww] * Xp + wX[ww];
  float Ae = __shfl_up(Ac, 1), Xe = __shfl_up(Xc, 1);
  if (lane == 0) { Ae = 1.f; Xe = 0.f; }
  float h = Ae * Xp + Xe;   // state entering this thread's 8 elements
  float o[8];
#pragma unroll
  for (int i = 0; i < 8; ++i) { h = a[i] * h + xv[i]; o[i] = h; }
  *(float4*)&hs_t[base + t * 8]     = *(const float4*)&o[0];
  *(float4*)&hs_t[base + t * 8 + 4] = *(const float4*)&o[4];
}

// ---------------- kernel 4: y = hs @ C ----------------
__global__ __launch_bounds__(512) void proj(const float* __restrict__ hs_t,
                                            const float* __restrict__ C,
                                            float* __restrict__ y) {
  __shared__ float sh[32 * 16];
  const int t = threadIdx.x;
  const int bB = blockIdx.x >> 6;
  const int s0 = (blockIdx.x & 63) * 32;
  const long row0 = (long)blockIdx.x * 32;
  {
    const int r = t >> 4, nn = t & 15;
    sh[r * 16 + nn] = hs_t[((long)bB * 16 + nn) * 2048 + s0 + r];
  }
  float4 c[16];
#pragma unroll
  for (int nn = 0; nn < 16; ++nn) c[nn] = *(const float4*)&C[nn * DMODEL + t * 4];
  __syncthreads();
#pragma unroll 4
  for (int r = 0; r < 32; ++r) {
    const float* h = &sh[r * 16];
    float4 o = {0.f, 0.f, 0.f, 0.f};
#pragma unroll
    for (int nn = 0; nn < 16; ++nn) {
      float hv = h[nn];
      o.x += hv * c[nn].x; o.y += hv * c[nn].y;
      o.z += hv * c[nn].z; o.w += hv * c[nn].w;
    }
    *(float4*)&y[(row0 + r) * DMODEL + t * 4] = o;
  }
}

extern "C" void kernel_launch(void* const* d_in, const int* in_sizes, int n_in,
                              void* d_out, int out_size, void* d_ws, size_t ws_size,
                              hipStream_t stream) {
  const float* x    = (const float*)d_in[0];
  const float* Alog = (const float*)d_in[1];
  const float* Bm   = (const float*)d_in[2];
  const float* Cm   = (const float*)d_in[3];
  const float* dtw  = (const float*)d_in[4];
  const float* dtb  = (const float*)d_in[5];
  const float* dtpw = (const float*)d_in[6];
  float* y = (float*)d_out;

  char* w = (char*)d_ws;
  u16*   Wcb   = (u16*)w;   w += (size_t)32 * DMODEL * 2;   // 128 KB
  float* bias2 = (float*)w; w += 256;
  float* ab_t  = (float*)w; w += (size_t)64 * 2048 * 4;     // 512 KB
  float* xb_t  = (float*)w; w += (size_t)64 * 2048 * 4;     // 512 KB
  float* hs_t  = (float*)w; w += (size_t)64 * 2048 * 4;     // 512 KB

  build_wc<<<128, 256, 0, stream>>>(dtw, dtpw, dtb, Bm, Wcb, bias2);
  fused_main<<<512, 512, 0, stream>>>(x, Wcb, bias2, Alog, ab_t, xb_t);
  scan_k<<<64, 256, 0, stream>>>(ab_t, xb_t, hs_t);
  proj<<<256, 512, 0, stream>>>(hs_t, Cm, y);
}

// Round 5
// 53.727 us; speedup vs baseline: 2.5527x; 1.2581x over previous
//
#include <hip/hip_runtime.h>
#include <hip/hip_bf16.h>

typedef unsigned short u16;
typedef unsigned int u32;
typedef short s8v __attribute__((ext_vector_type(8)));
typedef float f4v __attribute__((ext_vector_type(4)));

#define DMODEL 2048

__device__ __forceinline__ u16 f2bf(float f) {
  unsigned u = __float_as_uint(f);
  u += 0x7fffu + ((u >> 16) & 1u);
  return (u16)(u >> 16);
}

__device__ __forceinline__ u32 pkbf(float lo, float hi) {
  __hip_bfloat162 h = __float22bfloat162_rn(make_float2(lo, hi));
  return *reinterpret_cast<const u32*>(&h);
}

// ---------------- kernel 1: Wcb[32][2048] bf16 (k-contiguous rows) ----------------
__global__ __launch_bounds__(256) void build_wc(const float* __restrict__ dtw,
                                                const float* __restrict__ dtpw,
                                                const float* __restrict__ dtb,
                                                const float* __restrict__ Bm,
                                                u16* __restrict__ Wcb,
                                                float* __restrict__ bias2) {
  __shared__ float spw[512 * 16];
  __shared__ float sdw[64][16];
  const int t = threadIdx.x;
  const int k0 = blockIdx.x * 16;
  for (int i = t; i < 2048; i += 256)
    *(float4*)&spw[i * 4] = *(const float4*)&dtpw[i * 4];
  const int kk = t >> 4, n = t & 15;
  const int srr = t >> 2, sc4 = (t & 3) * 4;
  float acc = 0.f;
  for (int rc = 0; rc < 8; ++rc) {
    __syncthreads();
    *(float4*)&sdw[srr][sc4] = *(const float4*)&dtw[(rc * 64 + srr) * DMODEL + k0 + sc4];
    __syncthreads();
#pragma unroll 8
    for (int rr = 0; rr < 64; ++rr)
      acc += sdw[rr][kk] * spw[(rc * 64 + rr) * 16 + n];
  }
  Wcb[n * DMODEL + k0 + kk] = f2bf(acc);
  Wcb[(16 + n) * DMODEL + k0 + kk] = f2bf(Bm[(k0 + kk) * 16 + n]);
  if (blockIdx.x == 0 && t < 16) {
    float s0 = 0.f, s1 = 0.f;
    for (int r = 0; r < 512; r += 2) {
      s0 += dtb[r] * spw[r * 16 + t];
      s1 += dtb[r + 1] * spw[(r + 1) * 16 + t];
    }
    bias2[t] = s0 + s1;
  }
}

// ---------------- kernel 2: fused  x -> (abar_t, xb_t, chunk summaries) ----------------
// 512 blocks x 8 waves; block = 16 x-rows (= one scan chunk); wave w owns K-chunk.
__global__ __launch_bounds__(512) void fused_main(const float* __restrict__ x,
                                                  const u16* __restrict__ Wcb,
                                                  const float* __restrict__ bias2,
                                                  const float* __restrict__ Alog,
                                                  float* __restrict__ abar_t,
                                                  float* __restrict__ xb_t,
                                                  float* __restrict__ As,
                                                  float* __restrict__ Xs) {
  __shared__ float red[8][8][64];   // 16 KB
  __shared__ float aL[16][17], xL[16][17];
  const int t = threadIdx.x, w = t >> 6, l = t & 63;
  const int lr = l & 15, lh = l >> 4;
  const int row0 = blockIdx.x * 16;
  const int k0 = w * 256;

  f4v acc0 = {0.f, 0.f, 0.f, 0.f}, acc1 = {0.f, 0.f, 0.f, 0.f};
  const float* xp  = x + (long)(row0 + lr) * DMODEL + k0 + lh * 8;
  const u16*   wp0 = Wcb + lr * DMODEL + k0 + lh * 8;
  const u16*   wp1 = Wcb + (16 + lr) * DMODEL + k0 + lh * 8;

#pragma unroll
  for (int ks = 0; ks < 8; ++ks) {
    f4v u0 = __builtin_nontemporal_load((const f4v*)(xp + ks * 32));
    f4v u1 = __builtin_nontemporal_load((const f4v*)(xp + ks * 32 + 4));
    union { u32 d[4]; s8v v; } pa;
    pa.d[0] = pkbf(u0[0], u0[1]); pa.d[1] = pkbf(u0[2], u0[3]);
    pa.d[2] = pkbf(u1[0], u1[1]); pa.d[3] = pkbf(u1[2], u1[3]);
    s8v b0 = *(const s8v*)(wp0 + ks * 32);
    s8v b1 = *(const s8v*)(wp1 + ks * 32);
    acc0 = __builtin_amdgcn_mfma_f32_16x16x32_bf16(pa.v, b0, acc0, 0, 0, 0);
    acc1 = __builtin_amdgcn_mfma_f32_16x16x32_bf16(pa.v, b1, acc1, 0, 0, 0);
  }
#pragma unroll
  for (int q = 0; q < 4; ++q) { red[q][w][l] = acc0[q]; red[4 + q][w][l] = acc1[q]; }
  __syncthreads();

  float s = 0.f;
#pragma unroll
  for (int ww = 0; ww < 8; ++ww) s += red[w][ww][l];

  const int n = lr;
  const int row = lh * 4 + (w & 3);
  const int b = row0 >> 11, srow = row0 & 2047;
  const long idx = ((long)b * 16 + n) * 2048 + srow + row;
  if (w < 4) {
    float d2 = s + bias2[n];
    float sig = 1.f / (1.f + __expf(-d2));
    float delta = 0.001f + 0.099f * sig;
    float av = __expf(delta * __expf(Alog[n]));
    abar_t[idx] = av;
    aL[row][n] = av;
  } else {
    xb_t[idx] = s;
    xL[row][n] = s;
  }
  __syncthreads();
  if (t < 16) {
    float A = 1.f, X = 0.f;
#pragma unroll
    for (int r = 0; r < 16; ++r) {
      float a = aL[r][t];
      X = a * X + xL[r][t];
      A *= a;
    }
    const int chunk = srow >> 4;
    As[((long)b * 16 + t) * 128 + chunk] = A;
    Xs[((long)b * 16 + t) * 128 + chunk] = X;
  }
}

// ---------------- kernel 3: scan the 128 chunk summaries per (b,n) -> H0 ----------------
// 16 blocks x 4 waves; wave = one (b,n); lane holds chunks 2l, 2l+1.
__global__ __launch_bounds__(256) void scan_sum(const float* __restrict__ As,
                                                const float* __restrict__ Xs,
                                                float* __restrict__ H0) {
  const int t = threadIdx.x, w = t >> 6, lane = t & 63;
  const long bn = blockIdx.x * 4 + w;
  float a0 = As[bn * 128 + 2 * lane], x0 = Xs[bn * 128 + 2 * lane];
  float a1 = As[bn * 128 + 2 * lane + 1], x1 = Xs[bn * 128 + 2 * lane + 1];
  float Ac = a1 * a0, Xc = a1 * x0 + x1;   // compose chunk 2l then 2l+1
#pragma unroll
  for (int d = 1; d < 64; d <<= 1) {
    float pa = __shfl_up(Ac, d);
    float px = __shfl_up(Xc, d);
    if (lane >= d) { Xc = Ac * px + Xc; Ac = Ac * pa; }
  }
  float Xprev = __shfl_up(Xc, 1);
  if (lane == 0) Xprev = 0.f;
  H0[bn * 128 + 2 * lane]     = Xprev;            // state entering chunk 2l
  H0[bn * 128 + 2 * lane + 1] = a0 * Xprev + x0;  // state entering chunk 2l+1
}

// ---------------- kernel 4: reconstruct h + y = hs @ C ----------------
__global__ __launch_bounds__(512) void proj(const float* __restrict__ abar_t,
                                            const float* __restrict__ xb_t,
                                            const float* __restrict__ H0,
                                            const float* __restrict__ C,
                                            float* __restrict__ y) {
  __shared__ float sh[32 * 16];
  __shared__ float sa[16][32], sx[16][32];
  const int t = threadIdx.x;
  const int bB = blockIdx.x >> 6;
  const int s0 = (blockIdx.x & 63) * 32;
  const long row0 = (long)blockIdx.x * 32;
  {
    const int n = t >> 5, ss = t & 31;
    const long bn = (long)bB * 16 + n;
    sa[n][ss] = abar_t[bn * 2048 + s0 + ss];
    sx[n][ss] = xb_t[bn * 2048 + s0 + ss];
  }
  float4 c[16];
#pragma unroll
  for (int nn = 0; nn < 16; ++nn) c[nn] = *(const float4*)&C[nn * DMODEL + t * 4];
  __syncthreads();
  if (t < 32) {
    const int n = t & 15, cc = t >> 4;
    const long bn = (long)bB * 16 + n;
    float h = H0[bn * 128 + (s0 >> 4) + cc];
#pragma unroll
    for (int i = 0; i < 16; ++i) {
      int r = cc * 16 + i;
      h = sa[n][r] * h + sx[n][r];
      sh[r * 16 + n] = h;
    }
  }
  __syncthreads();
#pragma unroll 4
  for (int r = 0; r < 32; ++r) {
    const float* h = &sh[r * 16];
    f4v o = {0.f, 0.f, 0.f, 0.f};
#pragma unroll
    for (int nn = 0; nn < 16; ++nn) {
      float hv = h[nn];
      o[0] += hv * c[nn].x; o[1] += hv * c[nn].y;
      o[2] += hv * c[nn].z; o[3] += hv * c[nn].w;
    }
    __builtin_nontemporal_store(o, (f4v*)&y[(row0 + r) * DMODEL + t * 4]);
  }
}

extern "C" void kernel_launch(void* const* d_in, const int* in_sizes, int n_in,
                              void* d_out, int out_size, void* d_ws, size_t ws_size,
                              hipStream_t stream) {
  const float* x    = (const float*)d_in[0];
  const float* Alog = (const float*)d_in[1];
  const float* Bm   = (const float*)d_in[2];
  const float* Cm   = (const float*)d_in[3];
  const float* dtw  = (const float*)d_in[4];
  const float* dtb  = (const float*)d_in[5];
  const float* dtpw = (const float*)d_in[6];
  float* y = (float*)d_out;

  char* w = (char*)d_ws;
  u16*   Wcb   = (u16*)w;   w += (size_t)32 * DMODEL * 2;   // 128 KB
  float* bias2 = (float*)w; w += 256;
  float* ab_t  = (float*)w; w += (size_t)64 * 2048 * 4;     // 512 KB
  float* xb_t  = (float*)w; w += (size_t)64 * 2048 * 4;     // 512 KB
  float* As    = (float*)w; w += (size_t)64 * 128 * 4;      // 32 KB
  float* Xs    = (float*)w; w += (size_t)64 * 128 * 4;      // 32 KB
  float* H0    = (float*)w; w += (size_t)64 * 128 * 4;      // 32 KB

  build_wc<<<128, 256, 0, stream>>>(dtw, dtpw, dtb, Bm, Wcb, bias2);
  fused_main<<<512, 512, 0, stream>>>(x, Wcb, bias2, Alog, ab_t, xb_t, As, Xs);
  scan_sum<<<16, 256, 0, stream>>>(As, Xs, H0);
  proj<<<256, 512, 0, stream>>>(ab_t, xb_t, H0, Cm, y);
}